// Round 2
// baseline (3500.214 us; speedup 1.0000x reference)
//
#include <hip/hip_runtime.h>

// Problem constants (from reference)
#define T_STEPS 100
#define BATCH   32
#define NIN     512
#define NN      2048
#define AREAS   2

// ALPHA = float(np.exp(-1e-3/1e-2)); cast to f32 at use-site.
#define ALPHA_D 0.9048374180359595

// ---------------------------------------------------------------------------
// k0: Poisson input spikes for ALL timesteps. f32 compare semantics.
__global__ __launch_bounds__(256)
void k0_xi(const float* __restrict__ rates, const float* __restrict__ noise,
           float* __restrict__ outXi, unsigned* __restrict__ xi_mask)
{
    int el = blockIdx.x * 256 + threadIdx.x;      // exact grid: 1,638,400
    float r = rates[el], nz = noise[el];
    float p = __fmul_rn(r, 0.001f);
    int spike = (nz < p) ? 1 : 0;
    outXi[el] = (float)spike;
    if (spike) {
        int t = el >> 14;
        int b = (el >> 9) & 31;
        int i = el & (NIN - 1);
        atomicOr(&xi_mask[(t * 32 + b) * 16 + (i >> 5)], 1u << (i & 31));
    }
}

// ---------------------------------------------------------------------------
// k_ff: feedforward currents Iff[t][b][a][n], one block per (tb, a).
// Runs at full-GPU parallelism (6400 blocks) -- kept separate from the
// sequential step kernel on purpose.
__global__ __launch_bounds__(256)
void k_ff(const float* __restrict__ Win, const unsigned* __restrict__ xi_mask,
          float* __restrict__ Iff)
{
    const int tb  = blockIdx.x;      // t*32+b
    const int a   = blockIdx.y;
    const int tid = threadIdx.x;     // cols [8*tid, 8*tid+8)

    __shared__ unsigned mws[16];
    if (tid < 16) mws[tid] = xi_mask[tb * 16 + tid];
    __syncthreads();

    const float* Wa = Win + ((size_t)a << 20) + (tid << 3);
    float4 A0 = {0,0,0,0}, A1 = {0,0,0,0};
    for (int w = 0; w < 16; ++w) {
        unsigned mw = mws[w];
        int base_i = w << 5;
        while (mw) {
            int i = base_i + (__ffs(mw) - 1);
            mw &= mw - 1;
            const float* rp = Wa + ((size_t)i << 11);
            float4 w0 = ((const float4*)rp)[0];
            float4 w1 = ((const float4*)rp)[1];
            A0.x += w0.x; A0.y += w0.y; A0.z += w0.z; A0.w += w0.w;
            A1.x += w1.x; A1.y += w1.y; A1.z += w1.z; A1.w += w1.w;
        }
    }
    float* op = Iff + (((size_t)tb * 2 + a) << 11) + (tid << 3);
    ((float4*)op)[0] = A0;
    ((float4*)op)[1] = A1;
}

// ---------------------------------------------------------------------------
// k_steps: ONE BLOCK PER BATCH, 1024 threads. The previous 16-blocks/batch
// design exchanged spike masks through device-scope atomic RMWs: ~70k
// coherence-point RMWs per step (512 blocks x 128-word atomicOr reads +
// clears + barrier polls) -> ~14.5us/step of pure CP serialization while
// VALU/HBM sat idle (13.6% / 12%). Collapsing a batch into a single block
// moves ALL spike exchange into LDS + __syncthreads: zero global atomics,
// zero global barriers, no cooperative launch.
// Thread tid owns (dst area a = tid>>9, columns c..c+3, c = 4*(tid&511)).
// Gather preserves the bit-exact contraction: ascending (s, n_src) row
// order, serial __fadd_rn per column, accr starts at 0, I = accf + accr.
__global__ __launch_bounds__(1024)
void k_steps(const float* __restrict__ Wrec,
             const float* __restrict__ Iff,     // [t][b][a][n]
             float* __restrict__ outS)          // out + T*B*NIN
{
    const int tid = threadIdx.x;                // 0..1023
    const int b   = blockIdx.x;                 // batch
    const int a   = tid >> 9;                   // dst area
    const int c   = (tid & 511) << 2;           // dst column base (x4)

    __shared__ unsigned msk[2][128];            // double-buffered spike masks
    __shared__ __align__(16) unsigned short lrec[AREAS * NN];  // sorted spike list
    __shared__ int base[128];
    __shared__ int cnt_rec;

    if (tid < 128) msk[0][tid] = 0u;            // Xd(t=-1) = 0
    __syncthreads();

    // row slice base for this thread: Wrec[s][a][n][c], offset = s<<23 + n<<11
    const float* Wa = Wrec + ((size_t)a << 22) + c;
    const int rr_self = (a << 11) | c;
    const int wsel = rr_self >> 5;
    const int bsh  = rr_self & 31;

    float4 vst = {0.f, 0.f, 0.f, 0.f};

    for (int t = 0; t < T_STEPS; ++t) {
        unsigned* cm = msk[t & 1];              // spikes from t-1 (= Xd)
        unsigned* nm = msk[(t + 1) & 1];        // spikes produced at t

        // ---- phase 1: zero next-mask; wave-0 prefix scan of current mask
        if (tid < 128) nm[tid] = 0u;
        if (tid < 64) {
            int c0 = __popc(cm[2 * tid]), c1 = __popc(cm[2 * tid + 1]);
            int cc = c0 + c1, incl = cc;
            #pragma unroll
            for (int d = 1; d < 64; d <<= 1) {
                int v = __shfl_up(incl, d, 64);
                if (tid >= d) incl += v;
            }
            base[2 * tid]     = incl - cc;
            base[2 * tid + 1] = incl - c1;
            if (tid == 63) cnt_rec = incl;
        }
        __syncthreads();

        // ---- phase 2: expand mask to ascending row list
        if (tid < 128) {
            unsigned w = cm[tid];
            if (w) {
                int off = base[tid];
                int bb = tid << 5;
                while (w) {
                    int p = __ffs(w) - 1;
                    lrec[off++] = (unsigned short)(bb + p);
                    w &= w - 1;
                }
            }
        }
        __syncthreads();

        const int nrec = cnt_rec;

        // feedforward current (issued before the gather to overlap latency)
        float4 accf = *(const float4*)
            &Iff[((((size_t)t * BATCH + b) * 2 + a) << 11) + c];

        // ---- phase 3: recurrent gather, 4-deep float4 pipeline,
        //      ascending rows, serial f32 adds per column (bit-exact) ------
#define ROFF(rr) ((((rr) >> 11) << 23) + (((rr) & 2047) << 11))
#define ACC4(P)  { acc.x = __fadd_rn(acc.x, P.x); acc.y = __fadd_rn(acc.y, P.y); \
                   acc.z = __fadd_rn(acc.z, P.z); acc.w = __fadd_rn(acc.w, P.w); }
        float4 acc = {0.f, 0.f, 0.f, 0.f};
        int j = 0;
        if (nrec >= 4) {
            uint2 u = *(const uint2*)&lrec[0];
            int r0 = (int)(u.x & 0xffff), r1 = (int)(u.x >> 16);
            int r2 = (int)(u.y & 0xffff), r3 = (int)(u.y >> 16);
            float4 p0 = *(const float4*)(Wa + ROFF(r0));
            float4 p1 = *(const float4*)(Wa + ROFF(r1));
            float4 p2 = *(const float4*)(Wa + ROFF(r2));
            float4 p3 = *(const float4*)(Wa + ROFF(r3));
            for (j = 4; j + 4 <= nrec; j += 4) {
                uint2 v = *(const uint2*)&lrec[j];
                int n0 = (int)(v.x & 0xffff), n1 = (int)(v.x >> 16);
                int n2 = (int)(v.y & 0xffff), n3 = (int)(v.y >> 16);
                float4 q0 = *(const float4*)(Wa + ROFF(n0));
                float4 q1 = *(const float4*)(Wa + ROFF(n1));
                float4 q2 = *(const float4*)(Wa + ROFF(n2));
                float4 q3 = *(const float4*)(Wa + ROFF(n3));
                ACC4(p0); ACC4(p1); ACC4(p2); ACC4(p3);
                p0 = q0; p1 = q1; p2 = q2; p3 = q3;
            }
            ACC4(p0); ACC4(p1); ACC4(p2); ACC4(p3);
        }
        for (; j < nrec; ++j) {
            int rr = lrec[j];
            float4 p = *(const float4*)(Wa + ROFF(rr));
            ACC4(p);
        }
#undef ACC4
#undef ROFF

        // ---- phase 4: LIF update, numpy f32 op-for-op ----
        unsigned xw = (cm[wsel] >> bsh) & 0xFu;
        float4 sv;
        unsigned nib = 0u;
#define LIF(K, BIT) { \
            float v  = __fmul_rn((float)ALPHA_D, vst.K); \
            if (xw & BIT) v = 0.0f; \
            float I  = __fadd_rn(accf.K, acc.K); \
            float vn = __fadd_rn(v, I); \
            vst.K = vn; \
            if (vn >= 1.0f) { sv.K = 1.0f; nib |= BIT; } else sv.K = 0.0f; \
        }
        LIF(x, 1u) LIF(y, 2u) LIF(z, 4u) LIF(w, 8u)
#undef LIF
        *(float4*)&outS[(size_t)a * (T_STEPS * BATCH * NN)
                        + (((size_t)t * BATCH + b) << 11) + c] = sv;
        if (nib) atomicOr(&nm[wsel], nib << bsh);

        __syncthreads();    // spikes(t) complete before next step's scan
    }
}

// ---------------------------------------------------------------------------
extern "C" void kernel_launch(void* const* d_in, const int* in_sizes, int n_in,
                              void* d_out, int out_size, void* d_ws, size_t ws_size,
                              hipStream_t stream)
{
    const float* rates = (const float*)d_in[0];
    const float* noise = (const float*)d_in[1];
    const float* Win   = (const float*)d_in[2];
    const float* Wrec  = (const float*)d_in[3];
    float* out = (float*)d_out;

    // workspace layout (bytes):
    //   [0, 204800)          xi_mask uint32[T][B][16]
    //   [204800, +52428800)  Iff     float[T][B][A][N]   (16B aligned)
    char* ws = (char*)d_ws;
    unsigned* xi_mask = (unsigned*)ws;
    float*    Iff     = (float*)(ws + 204800);

    hipMemsetAsync(d_ws, 0, 204800, stream);    // zero xi_mask

    k0_xi<<<6400, 256, 0, stream>>>(rates, noise, out, xi_mask);
    k_ff<<<dim3(3200, 2), 256, 0, stream>>>(Win, xi_mask, Iff);

    float* outS = out + (size_t)T_STEPS * BATCH * NIN;
    k_steps<<<32, 1024, 0, stream>>>(Wrec, Iff, outS);
}

// Round 3
// 1838.129 us; speedup vs baseline: 1.9042x; 1.9042x over previous
//
#include <hip/hip_runtime.h>

// Problem constants (from reference)
#define T_STEPS 100
#define BATCH   32
#define NIN     512
#define NN      2048
#define AREAS   2

// ALPHA = float(np.exp(-1e-3/1e-2)); cast to f32 at use-site.
#define ALPHA_D 0.9048374180359595

// s_waitcnt imm: vmcnt=0, expcnt=7, lgkmcnt=15 -> wait ONLY on vmem completion
#define WAITCNT_VM0 0x0F70

// ---------------------------------------------------------------------------
// k0: Poisson input spikes for ALL timesteps. f32 compare semantics.
__global__ __launch_bounds__(256)
void k0_xi(const float* __restrict__ rates, const float* __restrict__ noise,
           float* __restrict__ outXi, unsigned* __restrict__ xi_mask)
{
    int el = blockIdx.x * 256 + threadIdx.x;      // exact grid: 1,638,400
    float r = rates[el], nz = noise[el];
    float p = __fmul_rn(r, 0.001f);
    int spike = (nz < p) ? 1 : 0;
    outXi[el] = (float)spike;
    if (spike) {
        int t = el >> 14;
        int b = (el >> 9) & 31;
        int i = el & (NIN - 1);
        atomicOr(&xi_mask[(t * 32 + b) * 16 + (i >> 5)], 1u << (i & 31));
    }
}

// ---------------------------------------------------------------------------
// k_ff: feedforward currents Iff[t][b][a][n], one block per (tb, a).
__global__ __launch_bounds__(256)
void k_ff(const float* __restrict__ Win, const unsigned* __restrict__ xi_mask,
          float* __restrict__ Iff)
{
    const int tb  = blockIdx.x;      // t*32+b
    const int a   = blockIdx.y;
    const int tid = threadIdx.x;     // cols [8*tid, 8*tid+8)

    __shared__ unsigned mws[16];
    if (tid < 16) mws[tid] = xi_mask[tb * 16 + tid];
    __syncthreads();

    const float* Wa = Win + ((size_t)a << 20) + (tid << 3);
    float4 A0 = {0,0,0,0}, A1 = {0,0,0,0};
    for (int w = 0; w < 16; ++w) {
        unsigned mw = mws[w];
        int base_i = w << 5;
        while (mw) {
            int i = base_i + (__ffs(mw) - 1);
            mw &= mw - 1;
            const float* rp = Wa + ((size_t)i << 11);
            float4 w0 = ((const float4*)rp)[0];
            float4 w1 = ((const float4*)rp)[1];
            A0.x += w0.x; A0.y += w0.y; A0.z += w0.z; A0.w += w0.w;
            A1.x += w1.x; A1.y += w1.y; A1.z += w1.z; A1.w += w1.w;
        }
    }
    float* op = Iff + (((size_t)tb * 2 + a) << 11) + (tid << 3);
    ((float4*)op)[0] = A0;
    ((float4*)op)[1] = A1;
}

// ---------------------------------------------------------------------------
// k_steps v3: 512 blocks = 32 batches x 16 column-slices, 256 threads each
// (thread = one dst column). Post-mortems:
//   R0 (16 blk/batch): sync-bound -- 65k coherence-point RMWs/step (atomicOr
//       mask READS) = 14.5us/step, VALU 13% HBM 12%.
//   R2 (1 blk/batch): per-CU BW-bound -- 32 CUs active, 41 GB/s/CU pull,
//       33.7us/step, VALU 1.9%.
// This version keeps 512-block parallelism but reads the spike masks with
// COALESCED agent-scope atomic loads (global_load sc1: coherent at the
// coherence point where producer atomics execute, but coalesces like a
// normal load -- no RMW serialization). Producers write their OWN 8 mask
// words by atomicExch (no clear pass, double-buffer suffices). Ordering:
// s_waitcnt vmcnt(0) before the per-batch barrier add (R0's proven rule).
// Per-step atomic RMW count: 512x8 exch + 512 add = 4.6k (was 65k).
// Slice s -> XCD s%8 (bx%8 heuristic): each XCD serves a fixed 8 MB
// column-stripe of Wrec -> partial L2 residency + cross-batch row reuse.
// Gather keeps bit-exact ascending (s,n) serial __fadd_rn order.
__global__ __launch_bounds__(256, 2)
void k_steps(const float* __restrict__ Wrec,
             unsigned* __restrict__ smask,      // [2][B][128]
             unsigned* __restrict__ bar,        // [B][16] (64B stride per b)
             const float* __restrict__ Iff,     // [t][b][a][n]
             float* __restrict__ outS)          // out + T*B*NIN
{
    const int tid = threadIdx.x;               // 0..255
    const int bx  = blockIdx.x;                // b*16 + s  (XCD = s%8)
    const int s   = bx & 15;
    const int b   = bx >> 4;
    const int a   = s >> 3;                    // dst area
    const int m0  = (s & 7) << 8;              // column-slice base
    const int c   = m0 + tid;                  // this thread's dst column

    __shared__ unsigned mws[128];
    __shared__ __align__(16) unsigned short lrec[AREAS * NN];  // 8 KB
    __shared__ int base[128];
    __shared__ int cnt_rec;
    __shared__ unsigned nsp[8];

    const float* __restrict__ Wa = Wrec + ((size_t)a << 22) + c;
    const int rr_self = (a << 11) | c;
    const int wsel = rr_self >> 5;
    const int w0   = s << 3;                   // this block's 8 owned words
    unsigned* mybar = bar + (b << 4);

    float vst = 0.0f;

    for (int t = 0; t < T_STEPS; ++t) {
        unsigned* cur = smask + (t & 1) * (BATCH * 128) + (b << 7);
        unsigned* nxt = smask + ((t + 1) & 1) * (BATCH * 128) + (b << 7);

        // ---- phase 1: coherent coalesced mask read (agent scope = sc1,
        //      reads the coherence point where producer atomics landed)
        if (tid < 128)
            mws[tid] = __hip_atomic_load(&cur[tid], __ATOMIC_RELAXED,
                                         __HIP_MEMORY_SCOPE_AGENT);
        if (tid < 8) nsp[tid] = 0u;
        // feedforward current: issue early, consumed after the gather
        float accf = Iff[((((size_t)t * BATCH + b) * 2 + a) << 11) + c];
        __syncthreads();

        // ---- phase 2: wave-0 prefix scan of mask popcounts
        if (tid < 64) {
            int c0 = __popc(mws[2 * tid]), c1 = __popc(mws[2 * tid + 1]);
            int cc = c0 + c1, incl = cc;
            #pragma unroll
            for (int d = 1; d < 64; d <<= 1) {
                int v = __shfl_up(incl, d, 64);
                if (tid >= d) incl += v;
            }
            base[2 * tid]     = incl - cc;
            base[2 * tid + 1] = incl - c1;
            if (tid == 63) cnt_rec = incl;
        }
        __syncthreads();

        // ---- phase 3: expand mask to ascending row list
        if (tid < 128) {
            unsigned w = mws[tid];
            if (w) {
                int off = base[tid];
                int bb = tid << 5;
                while (w) {
                    int p = __ffs(w) - 1;
                    lrec[off++] = (unsigned short)(bb + p);
                    w &= w - 1;
                }
            }
        }
        __syncthreads();

        const int nrec = cnt_rec;
        unsigned xd = (mws[wsel] >> (tid & 31)) & 1u;

        // ---- phase 4: recurrent gather, 8-deep pipeline, ascending rows,
        //      serial f32 adds (bit-exact) --------------------------------
#define OFF_OF(rr) ((((rr) >> 11) << 23) + (((rr) & 2047) << 11))
        float accr = 0.0f;
        int j = 0;
        if (nrec >= 8) {
            uint4 u = *(const uint4*)&lrec[0];
            int o0 = OFF_OF((int)(u.x & 0xffff)), o1 = OFF_OF((int)(u.x >> 16));
            int o2 = OFF_OF((int)(u.y & 0xffff)), o3 = OFF_OF((int)(u.y >> 16));
            int o4 = OFF_OF((int)(u.z & 0xffff)), o5 = OFF_OF((int)(u.z >> 16));
            int o6 = OFF_OF((int)(u.w & 0xffff)), o7 = OFF_OF((int)(u.w >> 16));
            float p0 = Wa[o0], p1 = Wa[o1], p2 = Wa[o2], p3 = Wa[o3];
            float p4 = Wa[o4], p5 = Wa[o5], p6 = Wa[o6], p7 = Wa[o7];
            for (j = 8; j + 8 <= nrec; j += 8) {
                uint4 v = *(const uint4*)&lrec[j];
                int n0 = OFF_OF((int)(v.x & 0xffff)), n1 = OFF_OF((int)(v.x >> 16));
                int n2 = OFF_OF((int)(v.y & 0xffff)), n3 = OFF_OF((int)(v.y >> 16));
                int n4 = OFF_OF((int)(v.z & 0xffff)), n5 = OFF_OF((int)(v.z >> 16));
                int n6 = OFF_OF((int)(v.w & 0xffff)), n7 = OFF_OF((int)(v.w >> 16));
                float q0 = Wa[n0], q1 = Wa[n1], q2 = Wa[n2], q3 = Wa[n3];
                float q4 = Wa[n4], q5 = Wa[n5], q6 = Wa[n6], q7 = Wa[n7];
                accr = __fadd_rn(accr, p0); accr = __fadd_rn(accr, p1);
                accr = __fadd_rn(accr, p2); accr = __fadd_rn(accr, p3);
                accr = __fadd_rn(accr, p4); accr = __fadd_rn(accr, p5);
                accr = __fadd_rn(accr, p6); accr = __fadd_rn(accr, p7);
                p0 = q0; p1 = q1; p2 = q2; p3 = q3;
                p4 = q4; p5 = q5; p6 = q6; p7 = q7;
            }
            accr = __fadd_rn(accr, p0); accr = __fadd_rn(accr, p1);
            accr = __fadd_rn(accr, p2); accr = __fadd_rn(accr, p3);
            accr = __fadd_rn(accr, p4); accr = __fadd_rn(accr, p5);
            accr = __fadd_rn(accr, p6); accr = __fadd_rn(accr, p7);
        }
        for (; j < nrec; ++j) {
            int rr = lrec[j];
            accr = __fadd_rn(accr, Wa[OFF_OF(rr)]);
        }
#undef OFF_OF

        // ---- phase 5: LIF update, numpy f32 op-for-op ----
        float I  = __fadd_rn(accf, accr);
        float v  = __fmul_rn((float)ALPHA_D, vst);
        if (xd) v = 0.0f;
        float vn = __fadd_rn(v, I);
        vst = vn;
        int S = (vn >= 1.0f) ? 1 : 0;
        outS[(size_t)a * (T_STEPS * BATCH * NN) + (((size_t)t * BATCH + b) << 11) + c]
            = (float)S;
        if (S) atomicOr(&nsp[tid >> 5], 1u << (tid & 31));

        if (t == T_STEPS - 1) break;           // last step: no exchange needed

        __syncthreads();                       // nsp complete
        // ---- phase 6: publish owned mask words (device-scope, no-return)
        if (tid < 8) atomicExch(&nxt[w0 + tid], nsp[tid]);
        __syncthreads();                       // each wave drains its vmem

        // ---- phase 7: per-batch 16-block barrier ----
        if (tid == 0) {
            __builtin_amdgcn_s_waitcnt(WAITCNT_VM0);   // exch committed at CP
            atomicAdd(mybar, 1u);
            unsigned target = 16u * (unsigned)(t + 1);
            while (__hip_atomic_load(mybar, __ATOMIC_RELAXED,
                                     __HIP_MEMORY_SCOPE_AGENT) < target)
                __builtin_amdgcn_s_sleep(2);
        }
        __syncthreads();
    }
}

// ---------------------------------------------------------------------------
extern "C" void kernel_launch(void* const* d_in, const int* in_sizes, int n_in,
                              void* d_out, int out_size, void* d_ws, size_t ws_size,
                              hipStream_t stream)
{
    const float* rates = (const float*)d_in[0];
    const float* noise = (const float*)d_in[1];
    const float* Win   = (const float*)d_in[2];
    const float* Wrec  = (const float*)d_in[3];
    float* out = (float*)d_out;

    // workspace layout (bytes):
    //   [0, 204800)           xi_mask uint32[T][B][16]
    //   [204800, 237568)      smask   uint32[2][B][128]
    //   [237568, 239616)      bar     uint32[B][16]
    //   [239616, +52428800)   Iff     float[T][B][A][N]  (16B aligned)
    char* ws = (char*)d_ws;
    unsigned* xi_mask = (unsigned*)ws;
    unsigned* smask   = (unsigned*)(ws + 204800);
    unsigned* bar     = (unsigned*)(ws + 237568);
    float*    Iff     = (float*)(ws + 239616);

    hipMemsetAsync(d_ws, 0, 239616, stream);   // zero xi_mask + smask + bar

    k0_xi<<<6400, 256, 0, stream>>>(rates, noise, out, xi_mask);
    k_ff<<<dim3(3200, 2), 256, 0, stream>>>(Win, xi_mask, Iff);

    float* outS = out + (size_t)T_STEPS * BATCH * NIN;
    void* args[] = { (void*)&Wrec, (void*)&smask, (void*)&bar,
                     (void*)&Iff, (void*)&outS };
    hipLaunchCooperativeKernel((const void*)k_steps, dim3(512), dim3(256),
                               args, 0, stream);
}

// Round 4
// 1375.404 us; speedup vs baseline: 2.5449x; 1.3364x over previous
//
#include <hip/hip_runtime.h>

// Problem constants (from reference)
#define T_STEPS 100
#define BATCH   32
#define NIN     512
#define NN      2048
#define AREAS   2

// ALPHA = float(np.exp(-1e-3/1e-2)); cast to f32 at use-site.
#define ALPHA_D 0.9048374180359595

// s_waitcnt imm: vmcnt=0, expcnt=7, lgkmcnt=15 -> wait ONLY on vmem completion
#define WAITCNT_VM0 0x0F70

// ---------------------------------------------------------------------------
// k0: Poisson input spikes for ALL timesteps. f32 compare semantics.
__global__ __launch_bounds__(256)
void k0_xi(const float* __restrict__ rates, const float* __restrict__ noise,
           float* __restrict__ outXi, unsigned* __restrict__ xi_mask)
{
    int el = blockIdx.x * 256 + threadIdx.x;      // exact grid: 1,638,400
    float r = rates[el], nz = noise[el];
    float p = __fmul_rn(r, 0.001f);
    int spike = (nz < p) ? 1 : 0;
    outXi[el] = (float)spike;
    if (spike) {
        int t = el >> 14;
        int b = (el >> 9) & 31;
        int i = el & (NIN - 1);
        atomicOr(&xi_mask[(t * 32 + b) * 16 + (i >> 5)], 1u << (i & 31));
    }
}

// ---------------------------------------------------------------------------
// k_ff: feedforward currents Iff[t][b][a][n], one block per (tb, a).
__global__ __launch_bounds__(256)
void k_ff(const float* __restrict__ Win, const unsigned* __restrict__ xi_mask,
          float* __restrict__ Iff)
{
    const int tb  = blockIdx.x;      // t*32+b
    const int a   = blockIdx.y;
    const int tid = threadIdx.x;     // cols [8*tid, 8*tid+8)

    __shared__ unsigned mws[16];
    if (tid < 16) mws[tid] = xi_mask[tb * 16 + tid];
    __syncthreads();

    const float* Wa = Win + ((size_t)a << 20) + (tid << 3);
    float4 A0 = {0,0,0,0}, A1 = {0,0,0,0};
    for (int w = 0; w < 16; ++w) {
        unsigned mw = mws[w];
        int base_i = w << 5;
        while (mw) {
            int i = base_i + (__ffs(mw) - 1);
            mw &= mw - 1;
            const float* rp = Wa + ((size_t)i << 11);
            float4 w0 = ((const float4*)rp)[0];
            float4 w1 = ((const float4*)rp)[1];
            A0.x += w0.x; A0.y += w0.y; A0.z += w0.z; A0.w += w0.w;
            A1.x += w1.x; A1.y += w1.y; A1.z += w1.z; A1.w += w1.w;
        }
    }
    float* op = Iff + (((size_t)tb * 2 + a) << 11) + (tid << 3);
    ((float4*)op)[0] = A0;
    ((float4*)op)[1] = A1;
}

// ---------------------------------------------------------------------------
#define OFF_OF(rr) ((((rr) >> 11) << 23) + (((rr) & 2047) << 11))

// issue 8 gather loads for rows lp[0..7] into p[0..7] (compile-time indices)
__device__ __forceinline__ void issue8(const float* __restrict__ Wa,
                                       const unsigned short* lp, float* p)
{
    uint4 u = *(const uint4*)lp;
    p[0] = Wa[OFF_OF((int)(u.x & 0xffff))];
    p[1] = Wa[OFF_OF((int)(u.x >> 16))];
    p[2] = Wa[OFF_OF((int)(u.y & 0xffff))];
    p[3] = Wa[OFF_OF((int)(u.y >> 16))];
    p[4] = Wa[OFF_OF((int)(u.z & 0xffff))];
    p[5] = Wa[OFF_OF((int)(u.z >> 16))];
    p[6] = Wa[OFF_OF((int)(u.w & 0xffff))];
    p[7] = Wa[OFF_OF((int)(u.w >> 16))];
}

// ---------------------------------------------------------------------------
// k_steps v4: 512 blocks = 32 batches x 16 column-slices, 256 threads
// (thread = one dst column). Post-mortem history:
//   R0 (16 blk/batch, RMW mask reads): 14.5us/step.
//   R2 (1 blk/batch, 16 waves/CU, float4, D=4): 33.7us/step but 41 GB/s/CU.
//   R3 (=v3, coalesced sc1 mask reads, D=8 dword): 16.7us/step, 10.4 GB/s/CU.
// v3 vs R0 falsified the "atomic storm" theory (65k->4.6k RMWs changed
// nothing). The real law (R2 vs v3): per-CU gather delivery scales linearly
// with per-CU bytes-in-flight (41 vs 10.4 GB/s at 64 vs 16 KB in flight);
// the gather is latency*MLP-bound (~1.5us loaded RT) and total lanes are
// fixed by the 128K columns -> the ONLY lever is pipeline depth.
// v4: depth 8 -> 32 rows in flight per lane (two-stage 32-groups, then
// 8-deep mid stage, then scalar tail). Add order stays STRICTLY ascending
// serial __fadd_rn -- bit-identical numerics. Also: publish masks BEFORE
// the outS store (earlier CP visibility), barrier poll via atomicAdd RMW
// (R0-proven; v3's sc1-load poll coincided with a 43ms cold-start anomaly).
__global__ __launch_bounds__(256, 2)
void k_steps(const float* __restrict__ Wrec,
             unsigned* __restrict__ smask,      // [2][B][128]
             unsigned* __restrict__ bar,        // [B][16] (64B stride per b)
             const float* __restrict__ Iff,     // [t][b][a][n]
             float* __restrict__ outS)          // out + T*B*NIN
{
    const int tid = threadIdx.x;               // 0..255
    const int bx  = blockIdx.x;                // b*16 + s  (XCD = s%8)
    const int s   = bx & 15;
    const int b   = bx >> 4;
    const int a   = s >> 3;                    // dst area
    const int m0  = (s & 7) << 8;              // column-slice base
    const int c   = m0 + tid;                  // this thread's dst column

    __shared__ unsigned mws[128];
    __shared__ __align__(16) unsigned short lrec[AREAS * NN];  // 8 KB
    __shared__ int base[128];
    __shared__ int cnt_rec;
    __shared__ unsigned nsp[8];

    const float* __restrict__ Wa = Wrec + ((size_t)a << 22) + c;
    const int rr_self = (a << 11) | c;
    const int wsel = rr_self >> 5;
    const int w0   = s << 3;                   // this block's 8 owned words
    unsigned* mybar = bar + (b << 4);

    float vst = 0.0f;

    for (int t = 0; t < T_STEPS; ++t) {
        unsigned* cur = smask + (t & 1) * (BATCH * 128) + (b << 7);
        unsigned* nxt = smask + ((t + 1) & 1) * (BATCH * 128) + (b << 7);

        // ---- phase 1: coherent coalesced mask read (agent scope)
        if (tid < 128)
            mws[tid] = __hip_atomic_load(&cur[tid], __ATOMIC_RELAXED,
                                         __HIP_MEMORY_SCOPE_AGENT);
        if (tid < 8) nsp[tid] = 0u;
        float accf = Iff[((((size_t)t * BATCH + b) * 2 + a) << 11) + c];
        __syncthreads();

        // ---- phase 2: wave-0 prefix scan of mask popcounts
        if (tid < 64) {
            int c0 = __popc(mws[2 * tid]), c1 = __popc(mws[2 * tid + 1]);
            int cc = c0 + c1, incl = cc;
            #pragma unroll
            for (int d = 1; d < 64; d <<= 1) {
                int v = __shfl_up(incl, d, 64);
                if (tid >= d) incl += v;
            }
            base[2 * tid]     = incl - cc;
            base[2 * tid + 1] = incl - c1;
            if (tid == 63) cnt_rec = incl;
        }
        __syncthreads();

        // ---- phase 3: expand mask to ascending row list
        if (tid < 128) {
            unsigned w = mws[tid];
            if (w) {
                int off = base[tid];
                int bb = tid << 5;
                while (w) {
                    int p = __ffs(w) - 1;
                    lrec[off++] = (unsigned short)(bb + p);
                    w &= w - 1;
                }
            }
        }
        __syncthreads();

        const int nrec = cnt_rec;
        unsigned xd = (mws[wsel] >> (tid & 31)) & 1u;

        // ---- phase 4: recurrent gather, 32-deep two-stage pipeline,
        //      ascending rows, serial f32 adds (bit-exact) ---------------
        float accr = 0.0f;
        int j = 0;
        if (nrec >= 32) {
            float p[32], q[32];
            issue8(Wa, &lrec[0],  p + 0);
            issue8(Wa, &lrec[8],  p + 8);
            issue8(Wa, &lrec[16], p + 16);
            issue8(Wa, &lrec[24], p + 24);
            for (j = 32; j + 32 <= nrec; j += 32) {
                issue8(Wa, &lrec[j],      q + 0);
                issue8(Wa, &lrec[j + 8],  q + 8);
                issue8(Wa, &lrec[j + 16], q + 16);
                issue8(Wa, &lrec[j + 24], q + 24);
                #pragma unroll
                for (int k = 0; k < 32; ++k) accr = __fadd_rn(accr, p[k]);
                #pragma unroll
                for (int k = 0; k < 32; ++k) p[k] = q[k];
            }
            #pragma unroll
            for (int k = 0; k < 32; ++k) accr = __fadd_rn(accr, p[k]);
        }
        if (nrec - j >= 8) {                    // 8-deep mid stage (<32 left)
            float p[8], q[8];
            issue8(Wa, &lrec[j], p);
            int jj = j + 8;
            for (; jj + 8 <= nrec; jj += 8) {
                issue8(Wa, &lrec[jj], q);
                #pragma unroll
                for (int k = 0; k < 8; ++k) accr = __fadd_rn(accr, p[k]);
                #pragma unroll
                for (int k = 0; k < 8; ++k) p[k] = q[k];
            }
            #pragma unroll
            for (int k = 0; k < 8; ++k) accr = __fadd_rn(accr, p[k]);
            j = jj;
        }
        for (; j < nrec; ++j) {                 // scalar tail (<8 left)
            int rr = lrec[j];
            accr = __fadd_rn(accr, Wa[OFF_OF(rr)]);
        }

        // ---- phase 5: LIF update, numpy f32 op-for-op ----
        float I  = __fadd_rn(accf, accr);
        float v  = __fmul_rn((float)ALPHA_D, vst);
        if (xd) v = 0.0f;
        float vn = __fadd_rn(v, I);
        vst = vn;
        int S = (vn >= 1.0f) ? 1 : 0;
        if (S) atomicOr(&nsp[tid >> 5], 1u << (tid & 31));
        __syncthreads();                       // nsp complete

        // ---- phase 6: publish masks FIRST (earlier CP visibility),
        //      then the (slow, unordered) outS store
        if (t < T_STEPS - 1 && tid < 8)
            atomicExch(&nxt[w0 + tid], nsp[tid]);
        outS[(size_t)a * (T_STEPS * BATCH * NN)
             + (((size_t)t * BATCH + b) << 11) + c] = (float)S;
        if (t == T_STEPS - 1) break;

        // ---- phase 7: per-batch 16-block barrier (RMW poll, R0-proven)
        if (tid == 0) {
            __builtin_amdgcn_s_waitcnt(WAITCNT_VM0);   // exch committed at CP
            atomicAdd(mybar, 1u);
            unsigned target = 16u * (unsigned)(t + 1);
            while (atomicAdd(mybar, 0u) < target)
                __builtin_amdgcn_s_sleep(4);
        }
        __syncthreads();
    }
}
#undef OFF_OF

// ---------------------------------------------------------------------------
extern "C" void kernel_launch(void* const* d_in, const int* in_sizes, int n_in,
                              void* d_out, int out_size, void* d_ws, size_t ws_size,
                              hipStream_t stream)
{
    const float* rates = (const float*)d_in[0];
    const float* noise = (const float*)d_in[1];
    const float* Win   = (const float*)d_in[2];
    const float* Wrec  = (const float*)d_in[3];
    float* out = (float*)d_out;

    // workspace layout (bytes):
    //   [0, 204800)           xi_mask uint32[T][B][16]
    //   [204800, 237568)      smask   uint32[2][B][128]
    //   [237568, 239616)      bar     uint32[B][16]
    //   [239616, +52428800)   Iff     float[T][B][A][N]  (16B aligned)
    char* ws = (char*)d_ws;
    unsigned* xi_mask = (unsigned*)ws;
    unsigned* smask   = (unsigned*)(ws + 204800);
    unsigned* bar     = (unsigned*)(ws + 237568);
    float*    Iff     = (float*)(ws + 239616);

    hipMemsetAsync(d_ws, 0, 239616, stream);   // zero xi_mask + smask + bar

    k0_xi<<<6400, 256, 0, stream>>>(rates, noise, out, xi_mask);
    k_ff<<<dim3(3200, 2), 256, 0, stream>>>(Win, xi_mask, Iff);

    float* outS = out + (size_t)T_STEPS * BATCH * NIN;
    void* args[] = { (void*)&Wrec, (void*)&smask, (void*)&bar,
                     (void*)&Iff, (void*)&outS };
    hipLaunchCooperativeKernel((const void*)k_steps, dim3(512), dim3(256),
                               args, 0, stream);
}

// Round 5
// 1220.584 us; speedup vs baseline: 2.8677x; 1.1268x over previous
//
#include <hip/hip_runtime.h>

// Problem constants (from reference)
#define T_STEPS 100
#define BATCH   32
#define NIN     512
#define NN      2048
#define AREAS   2

// ALPHA = float(np.exp(-1e-3/1e-2)); cast to f32 at use-site.
#define ALPHA_D 0.9048374180359595

// ---------------------------------------------------------------------------
// k0: Poisson input spikes for ALL timesteps. f32 compare semantics.
__global__ __launch_bounds__(256)
void k0_xi(const float* __restrict__ rates, const float* __restrict__ noise,
           float* __restrict__ outXi, unsigned* __restrict__ xi_mask)
{
    int el = blockIdx.x * 256 + threadIdx.x;      // exact grid: 1,638,400
    float r = rates[el], nz = noise[el];
    float p = __fmul_rn(r, 0.001f);
    int spike = (nz < p) ? 1 : 0;
    outXi[el] = (float)spike;
    if (spike) {
        int t = el >> 14;
        int b = (el >> 9) & 31;
        int i = el & (NIN - 1);
        atomicOr(&xi_mask[(t * 32 + b) * 16 + (i >> 5)], 1u << (i & 31));
    }
}

// ---------------------------------------------------------------------------
// k_ff: feedforward currents Iff[t][b][a][n], one block per (tb, a).
__global__ __launch_bounds__(256)
void k_ff(const float* __restrict__ Win, const unsigned* __restrict__ xi_mask,
          float* __restrict__ Iff)
{
    const int tb  = blockIdx.x;      // t*32+b
    const int a   = blockIdx.y;
    const int tid = threadIdx.x;     // cols [8*tid, 8*tid+8)

    __shared__ unsigned mws[16];
    if (tid < 16) mws[tid] = xi_mask[tb * 16 + tid];
    __syncthreads();

    const float* Wa = Win + ((size_t)a << 20) + (tid << 3);
    float4 A0 = {0,0,0,0}, A1 = {0,0,0,0};
    for (int w = 0; w < 16; ++w) {
        unsigned mw = mws[w];
        int base_i = w << 5;
        while (mw) {
            int i = base_i + (__ffs(mw) - 1);
            mw &= mw - 1;
            const float* rp = Wa + ((size_t)i << 11);
            float4 w0 = ((const float4*)rp)[0];
            float4 w1 = ((const float4*)rp)[1];
            A0.x += w0.x; A0.y += w0.y; A0.z += w0.z; A0.w += w0.w;
            A1.x += w1.x; A1.y += w1.y; A1.z += w1.z; A1.w += w1.w;
        }
    }
    float* op = Iff + (((size_t)tb * 2 + a) << 11) + (tid << 3);
    ((float4*)op)[0] = A0;
    ((float4*)op)[1] = A1;
}

// ---------------------------------------------------------------------------
#define OFF_OF(rr) ((((rr) >> 11) << 23) + (((rr) & 2047) << 11))

// issue 8 gather loads for rows lp[0..7] into p[0..7] (compile-time indices)
__device__ __forceinline__ void issue8(const float* __restrict__ Wa,
                                       const unsigned short* lp, float* p)
{
    uint4 u = *(const uint4*)lp;
    p[0] = Wa[OFF_OF((int)(u.x & 0xffff))];
    p[1] = Wa[OFF_OF((int)(u.x >> 16))];
    p[2] = Wa[OFF_OF((int)(u.y & 0xffff))];
    p[3] = Wa[OFF_OF((int)(u.y >> 16))];
    p[4] = Wa[OFF_OF((int)(u.z & 0xffff))];
    p[5] = Wa[OFF_OF((int)(u.z >> 16))];
    p[6] = Wa[OFF_OF((int)(u.w & 0xffff))];
    p[7] = Wa[OFF_OF((int)(u.w >> 16))];
}

// ---------------------------------------------------------------------------
// k_steps v5: 512 blocks = 32 batches x 16 column-slices, 256 threads.
// Post-mortem chain:
//   R0 14.5us/step; R2 (1blk/batch) 33.7; v3 (D=8) 16.7; v4 (D=32) 12.1.
// Fitting step = F + G(D) to v3/v4: gather G ~1.5-3us, FIXED F ~9-10us.
// F is the exchange serial chain: leader waitcnt(outS store!) -> barrier
// atomicAdd -> RMW poll (512 pollers x 32 addrs, serializing) -> sc1 mask
// read = ~3 sequential CP round trips + HBM store drain.
// v5: THE DATA IS THE BARRIER. Producers publish u64 (epoch<<32|mask) via
// atomicExch (CP-executing, R0/R4-proven). Consumers: each of 128 lanes
// spin-polls ITS OWN word with coalesced agent-scope (sc1) loads until
// tag==t. One CP RT replaces three; no RMW poll storms; no leader
// bottleneck; outS stores leave the critical path (no waitcnt at all).
// Safety: double-buffer + poll dependency => producer P overwrites a
// buffer with tag t+2 only after P passed its t+1 poll, which requires
// EVERY consumer C's end-of-t publish, which happens only after C's
// successful read of tag-t words. Tag mismatch spins (safe), never reads
// stale-as-fresh. Gather: v4's 32-deep pipeline, bit-exact ascending
// serial __fadd_rn order.
__global__ __launch_bounds__(256, 2)
void k_steps(const float* __restrict__ Wrec,
             unsigned long long* __restrict__ smask,  // [2][B][128] u64 tag|mask
             const float* __restrict__ Iff,           // [t][b][a][n]
             float* __restrict__ outS)                // out + T*B*NIN
{
    const int tid = threadIdx.x;               // 0..255
    const int bx  = blockIdx.x;                // b*16 + s  (XCD = s%8)
    const int s   = bx & 15;
    const int b   = bx >> 4;
    const int a   = s >> 3;                    // dst area
    const int m0  = (s & 7) << 8;              // column-slice base
    const int c   = m0 + tid;                  // this thread's dst column

    __shared__ unsigned mws[128];
    __shared__ __align__(16) unsigned short lrec[AREAS * NN];  // 8 KB
    __shared__ int base[128];
    __shared__ int cnt_rec;
    __shared__ unsigned nsp[8];

    const float* __restrict__ Wa = Wrec + ((size_t)a << 22) + c;
    const int rr_self = (a << 11) | c;
    const int wsel = rr_self >> 5;
    const int w0   = s << 3;                   // this block's 8 owned words

    float vst = 0.0f;

    for (int t = 0; t < T_STEPS; ++t) {
        unsigned long long* cur = smask + (size_t)(t & 1) * (BATCH * 128) + (b << 7);
        unsigned long long* nxt = smask + (size_t)((t + 1) & 1) * (BATCH * 128) + (b << 7);

        // ---- phase 1: data-spin -- each lane polls its own tagged word.
        //      Coalesced sc1 loads (no RMW serialization). memset gives
        //      tag0|mask0 => step 0 passes immediately with empty mask.
        if (tid < 128) {
            unsigned long long v = __hip_atomic_load(&cur[tid], __ATOMIC_RELAXED,
                                                     __HIP_MEMORY_SCOPE_AGENT);
            while ((unsigned)(v >> 32) != (unsigned)t) {
                __builtin_amdgcn_s_sleep(4);
                v = __hip_atomic_load(&cur[tid], __ATOMIC_RELAXED,
                                      __HIP_MEMORY_SCOPE_AGENT);
            }
            mws[tid] = (unsigned)v;
        }
        if (tid < 8) nsp[tid] = 0u;
        float accf = Iff[((((size_t)t * BATCH + b) * 2 + a) << 11) + c];
        __syncthreads();

        // ---- phase 2: wave-0 prefix scan of mask popcounts
        if (tid < 64) {
            int c0 = __popc(mws[2 * tid]), c1 = __popc(mws[2 * tid + 1]);
            int cc = c0 + c1, incl = cc;
            #pragma unroll
            for (int d = 1; d < 64; d <<= 1) {
                int v = __shfl_up(incl, d, 64);
                if (tid >= d) incl += v;
            }
            base[2 * tid]     = incl - cc;
            base[2 * tid + 1] = incl - c1;
            if (tid == 63) cnt_rec = incl;
        }
        __syncthreads();

        // ---- phase 3: expand mask to ascending row list
        if (tid < 128) {
            unsigned w = mws[tid];
            if (w) {
                int off = base[tid];
                int bb = tid << 5;
                while (w) {
                    int p = __ffs(w) - 1;
                    lrec[off++] = (unsigned short)(bb + p);
                    w &= w - 1;
                }
            }
        }
        __syncthreads();

        const int nrec = cnt_rec;
        unsigned xd = (mws[wsel] >> (tid & 31)) & 1u;

        // ---- phase 4: recurrent gather, 32-deep two-stage pipeline,
        //      ascending rows, serial f32 adds (bit-exact) ---------------
        float accr = 0.0f;
        int j = 0;
        if (nrec >= 32) {
            float p[32], q[32];
            issue8(Wa, &lrec[0],  p + 0);
            issue8(Wa, &lrec[8],  p + 8);
            issue8(Wa, &lrec[16], p + 16);
            issue8(Wa, &lrec[24], p + 24);
            for (j = 32; j + 32 <= nrec; j += 32) {
                issue8(Wa, &lrec[j],      q + 0);
                issue8(Wa, &lrec[j + 8],  q + 8);
                issue8(Wa, &lrec[j + 16], q + 16);
                issue8(Wa, &lrec[j + 24], q + 24);
                #pragma unroll
                for (int k = 0; k < 32; ++k) accr = __fadd_rn(accr, p[k]);
                #pragma unroll
                for (int k = 0; k < 32; ++k) p[k] = q[k];
            }
            #pragma unroll
            for (int k = 0; k < 32; ++k) accr = __fadd_rn(accr, p[k]);
        }
        if (nrec - j >= 8) {                    // 8-deep mid stage (<32 left)
            float p[8], q[8];
            issue8(Wa, &lrec[j], p);
            int jj = j + 8;
            for (; jj + 8 <= nrec; jj += 8) {
                issue8(Wa, &lrec[jj], q);
                #pragma unroll
                for (int k = 0; k < 8; ++k) accr = __fadd_rn(accr, p[k]);
                #pragma unroll
                for (int k = 0; k < 8; ++k) p[k] = q[k];
            }
            #pragma unroll
            for (int k = 0; k < 8; ++k) accr = __fadd_rn(accr, p[k]);
            j = jj;
        }
        for (; j < nrec; ++j) {                 // scalar tail (<8 left)
            int rr = lrec[j];
            accr = __fadd_rn(accr, Wa[OFF_OF(rr)]);
        }

        // ---- phase 5: LIF update, numpy f32 op-for-op ----
        float I  = __fadd_rn(accf, accr);
        float v  = __fmul_rn((float)ALPHA_D, vst);
        if (xd) v = 0.0f;
        float vn = __fadd_rn(v, I);
        vst = vn;
        int S = (vn >= 1.0f) ? 1 : 0;
        if (S) atomicOr(&nsp[tid >> 5], 1u << (tid & 31));
        __syncthreads();                       // nsp complete

        // ---- phase 6: publish tagged words FIRST (starts the CP round
        //      trip ASAP), then the off-critical-path outS store.
        if (t < T_STEPS - 1 && tid < 8) {
            unsigned long long pv =
                ((unsigned long long)(unsigned)(t + 1) << 32) | nsp[tid];
            atomicExch(&nxt[w0 + tid], pv);    // RMW executes at CP (m20)
        }
        outS[(size_t)a * (T_STEPS * BATCH * NN)
             + (((size_t)t * BATCH + b) << 11) + c] = (float)S;
        // next iteration's poll loads queue behind the exch in wave order;
        // no waitcnt, no barrier counters.
    }
}
#undef OFF_OF

// ---------------------------------------------------------------------------
extern "C" void kernel_launch(void* const* d_in, const int* in_sizes, int n_in,
                              void* d_out, int out_size, void* d_ws, size_t ws_size,
                              hipStream_t stream)
{
    const float* rates = (const float*)d_in[0];
    const float* noise = (const float*)d_in[1];
    const float* Win   = (const float*)d_in[2];
    const float* Wrec  = (const float*)d_in[3];
    float* out = (float*)d_out;

    // workspace layout (bytes):
    //   [0, 204800)           xi_mask uint32[T][B][16]
    //   [204800, 270336)      smask   u64[2][B][128]  (tag<<32 | mask)
    //   [270336, +52428800)   Iff     float[T][B][A][N]  (16B aligned)
    char* ws = (char*)d_ws;
    unsigned* xi_mask = (unsigned*)ws;
    unsigned long long* smask = (unsigned long long*)(ws + 204800);
    float* Iff = (float*)(ws + 270336);

    hipMemsetAsync(d_ws, 0, 270336, stream);   // zero xi_mask + smask

    k0_xi<<<6400, 256, 0, stream>>>(rates, noise, out, xi_mask);
    k_ff<<<dim3(3200, 2), 256, 0, stream>>>(Win, xi_mask, Iff);

    float* outS = out + (size_t)T_STEPS * BATCH * NIN;
    void* args[] = { (void*)&Wrec, (void*)&smask, (void*)&Iff, (void*)&outS };
    hipLaunchCooperativeKernel((const void*)k_steps, dim3(512), dim3(256),
                               args, 0, stream);
}

// Round 6
// 1125.180 us; speedup vs baseline: 3.1108x; 1.0848x over previous
//
#include <hip/hip_runtime.h>

// Problem constants (from reference)
#define T_STEPS 100
#define BATCH   32
#define NIN     512
#define NN      2048
#define AREAS   2

// ALPHA = float(np.exp(-1e-3/1e-2)); cast to f32 at use-site.
#define ALPHA_D 0.9048374180359595

// ---------------------------------------------------------------------------
// k0: Poisson input spikes for ALL timesteps. f32 compare semantics.
__global__ __launch_bounds__(256)
void k0_xi(const float* __restrict__ rates, const float* __restrict__ noise,
           float* __restrict__ outXi, unsigned* __restrict__ xi_mask)
{
    int el = blockIdx.x * 256 + threadIdx.x;      // exact grid: 1,638,400
    float r = rates[el], nz = noise[el];
    float p = __fmul_rn(r, 0.001f);
    int spike = (nz < p) ? 1 : 0;
    outXi[el] = (float)spike;
    if (spike) {
        int t = el >> 14;
        int b = (el >> 9) & 31;
        int i = el & (NIN - 1);
        atomicOr(&xi_mask[(t * 32 + b) * 16 + (i >> 5)], 1u << (i & 31));
    }
}

// ---------------------------------------------------------------------------
// k_ff: feedforward currents Iff[t][b][a][n], one block per (tb, a).
__global__ __launch_bounds__(256)
void k_ff(const float* __restrict__ Win, const unsigned* __restrict__ xi_mask,
          float* __restrict__ Iff)
{
    const int tb  = blockIdx.x;      // t*32+b
    const int a   = blockIdx.y;
    const int tid = threadIdx.x;     // cols [8*tid, 8*tid+8)

    __shared__ unsigned mws[16];
    if (tid < 16) mws[tid] = xi_mask[tb * 16 + tid];
    __syncthreads();

    const float* Wa = Win + ((size_t)a << 20) + (tid << 3);
    float4 A0 = {0,0,0,0}, A1 = {0,0,0,0};
    for (int w = 0; w < 16; ++w) {
        unsigned mw = mws[w];
        int base_i = w << 5;
        while (mw) {
            int i = base_i + (__ffs(mw) - 1);
            mw &= mw - 1;
            const float* rp = Wa + ((size_t)i << 11);
            float4 w0 = ((const float4*)rp)[0];
            float4 w1 = ((const float4*)rp)[1];
            A0.x += w0.x; A0.y += w0.y; A0.z += w0.z; A0.w += w0.w;
            A1.x += w1.x; A1.y += w1.y; A1.z += w1.z; A1.w += w1.w;
        }
    }
    float* op = Iff + (((size_t)tb * 2 + a) << 11) + (tid << 3);
    ((float4*)op)[0] = A0;
    ((float4*)op)[1] = A1;
}

// ---------------------------------------------------------------------------
#define OFF_OF(rr) ((((rr) >> 11) << 23) + (((rr) & 2047) << 11))

// issue 8 gather loads for rows lp[0..7] into p[0..7] (compile-time indices)
__device__ __forceinline__ void issue8(const float* __restrict__ Wa,
                                       const unsigned short* lp, float* p)
{
    uint4 u = *(const uint4*)lp;
    p[0] = Wa[OFF_OF((int)(u.x & 0xffff))];
    p[1] = Wa[OFF_OF((int)(u.x >> 16))];
    p[2] = Wa[OFF_OF((int)(u.y & 0xffff))];
    p[3] = Wa[OFF_OF((int)(u.y >> 16))];
    p[4] = Wa[OFF_OF((int)(u.z & 0xffff))];
    p[5] = Wa[OFF_OF((int)(u.z >> 16))];
    p[6] = Wa[OFF_OF((int)(u.w & 0xffff))];
    p[7] = Wa[OFF_OF((int)(u.w >> 16))];
}

__device__ __forceinline__ void issue32(const float* __restrict__ Wa,
                                        const unsigned short* lp, float* p)
{
    issue8(Wa, lp,      p);
    issue8(Wa, lp + 8,  p + 8);
    issue8(Wa, lp + 16, p + 16);
    issue8(Wa, lp + 24, p + 24);
}

// ---------------------------------------------------------------------------
// k_steps v6: 512 blocks = 32 batches x 16 column-slices, 256 threads.
// Post-mortem chain:
//   R0 14.5us/step; R2 33.7 (41 GB/s/CU @ 64KB in flight); v3 16.7;
//   v4 (D=32 "nominal") 12.1; v5 (data-is-the-barrier) 10.6.
// v5's VGPR_Count=52 exposed the real story: the compiler COMPRESSED the
// 32-deep pipeline (p[32]+q[32] staging needs >=64 VGPR live) into an
// interleaved issue/consume schedule with only ~10 loads outstanding
// (~20KB/CU in flight -> 40 GB/s/CU at RT~0.5us, which closes exactly).
// v4/v5 never ran at the programmed depth.
// v6: FORCE the depth with __builtin_amdgcn_sched_barrier(0) -- ping-pong
// banks: {issue32 q | BARRIER | 32 adds of p | issue32 p | BARRIER |
// 32 adds of q}. Loads cannot sink below the barrier, so all 32 must be
// issued (and register-allocated) before any consume. Steady state has no
// copy-movs. Add order stays STRICTLY ascending serial __fadd_rn.
// Everything else identical to v5 to isolate the effect. Verification
// signal: VGPR must jump to ~100; if it stays ~52 the scheduler defeated
// the barrier and the next move is an inline-asm gather loop.
__global__ __launch_bounds__(256, 2)
void k_steps(const float* __restrict__ Wrec,
             unsigned long long* __restrict__ smask,  // [2][B][128] u64 tag|mask
             const float* __restrict__ Iff,           // [t][b][a][n]
             float* __restrict__ outS)                // out + T*B*NIN
{
    const int tid = threadIdx.x;               // 0..255
    const int bx  = blockIdx.x;                // b*16 + s  (XCD = s%8)
    const int s   = bx & 15;
    const int b   = bx >> 4;
    const int a   = s >> 3;                    // dst area
    const int m0  = (s & 7) << 8;              // column-slice base
    const int c   = m0 + tid;                  // this thread's dst column

    __shared__ unsigned mws[128];
    __shared__ __align__(16) unsigned short lrec[AREAS * NN];  // 8 KB
    __shared__ int base[128];
    __shared__ int cnt_rec;
    __shared__ unsigned nsp[8];

    const float* __restrict__ Wa = Wrec + ((size_t)a << 22) + c;
    const int rr_self = (a << 11) | c;
    const int wsel = rr_self >> 5;
    const int w0   = s << 3;                   // this block's 8 owned words

    float vst = 0.0f;

    for (int t = 0; t < T_STEPS; ++t) {
        unsigned long long* cur = smask + (size_t)(t & 1) * (BATCH * 128) + (b << 7);
        unsigned long long* nxt = smask + (size_t)((t + 1) & 1) * (BATCH * 128) + (b << 7);

        // ---- phase 1: data-spin -- each lane polls its own tagged word.
        if (tid < 128) {
            unsigned long long v = __hip_atomic_load(&cur[tid], __ATOMIC_RELAXED,
                                                     __HIP_MEMORY_SCOPE_AGENT);
            while ((unsigned)(v >> 32) != (unsigned)t) {
                __builtin_amdgcn_s_sleep(4);
                v = __hip_atomic_load(&cur[tid], __ATOMIC_RELAXED,
                                      __HIP_MEMORY_SCOPE_AGENT);
            }
            mws[tid] = (unsigned)v;
        }
        if (tid < 8) nsp[tid] = 0u;
        float accf = Iff[((((size_t)t * BATCH + b) * 2 + a) << 11) + c];
        __syncthreads();

        // ---- phase 2: wave-0 prefix scan of mask popcounts
        if (tid < 64) {
            int c0 = __popc(mws[2 * tid]), c1 = __popc(mws[2 * tid + 1]);
            int cc = c0 + c1, incl = cc;
            #pragma unroll
            for (int d = 1; d < 64; d <<= 1) {
                int v = __shfl_up(incl, d, 64);
                if (tid >= d) incl += v;
            }
            base[2 * tid]     = incl - cc;
            base[2 * tid + 1] = incl - c1;
            if (tid == 63) cnt_rec = incl;
        }
        __syncthreads();

        // ---- phase 3: expand mask to ascending row list
        if (tid < 128) {
            unsigned w = mws[tid];
            if (w) {
                int off = base[tid];
                int bb = tid << 5;
                while (w) {
                    int p = __ffs(w) - 1;
                    lrec[off++] = (unsigned short)(bb + p);
                    w &= w - 1;
                }
            }
        }
        __syncthreads();

        const int nrec = cnt_rec;
        unsigned xd = (mws[wsel] >> (tid & 31)) & 1u;

        // ---- phase 4: recurrent gather, FORCED 32-deep ping-pong,
        //      ascending rows, serial f32 adds (bit-exact) ---------------
        float accr = 0.0f;
        int j = 0;
        if (nrec >= 32) {
            float p[32], q[32];
            issue32(Wa, &lrec[0], p);          // p = rows [0,32)
            j = 32;
            while (j + 64 <= nrec) {           // steady: 64 rows/iter
                issue32(Wa, &lrec[j], q);      // q = rows [j, j+32)
                __builtin_amdgcn_sched_barrier(0);
                #pragma unroll
                for (int k = 0; k < 32; ++k) accr = __fadd_rn(accr, p[k]);
                issue32(Wa, &lrec[j + 32], p); // p = rows [j+32, j+64)
                __builtin_amdgcn_sched_barrier(0);
                #pragma unroll
                for (int k = 0; k < 32; ++k) accr = __fadd_rn(accr, q[k]);
                j += 64;
            }
            if (j + 32 <= nrec) {              // one extra 32-bank
                issue32(Wa, &lrec[j], q);
                __builtin_amdgcn_sched_barrier(0);
                #pragma unroll
                for (int k = 0; k < 32; ++k) accr = __fadd_rn(accr, p[k]);
                #pragma unroll
                for (int k = 0; k < 32; ++k) p[k] = q[k];
                j += 32;
            }
            #pragma unroll
            for (int k = 0; k < 32; ++k) accr = __fadd_rn(accr, p[k]);
        }
        if (nrec - j >= 8) {                   // 8-deep mid stage (<32 left)
            float p8[8], q8[8];
            issue8(Wa, &lrec[j], p8);
            int jj = j + 8;
            for (; jj + 8 <= nrec; jj += 8) {
                issue8(Wa, &lrec[jj], q8);
                __builtin_amdgcn_sched_barrier(0);
                #pragma unroll
                for (int k = 0; k < 8; ++k) accr = __fadd_rn(accr, p8[k]);
                #pragma unroll
                for (int k = 0; k < 8; ++k) p8[k] = q8[k];
            }
            #pragma unroll
            for (int k = 0; k < 8; ++k) accr = __fadd_rn(accr, p8[k]);
            j = jj;
        }
        for (; j < nrec; ++j) {                // scalar tail (<8 left)
            int rr = lrec[j];
            accr = __fadd_rn(accr, Wa[OFF_OF(rr)]);
        }

        // ---- phase 5: LIF update, numpy f32 op-for-op ----
        float I  = __fadd_rn(accf, accr);
        float v  = __fmul_rn((float)ALPHA_D, vst);
        if (xd) v = 0.0f;
        float vn = __fadd_rn(v, I);
        vst = vn;
        int S = (vn >= 1.0f) ? 1 : 0;
        if (S) atomicOr(&nsp[tid >> 5], 1u << (tid & 31));
        __syncthreads();                       // nsp complete

        // ---- phase 6: publish tagged words FIRST, then outS store
        if (t < T_STEPS - 1 && tid < 8) {
            unsigned long long pv =
                ((unsigned long long)(unsigned)(t + 1) << 32) | nsp[tid];
            atomicExch(&nxt[w0 + tid], pv);    // RMW executes at CP (m20)
        }
        outS[(size_t)a * (T_STEPS * BATCH * NN)
             + (((size_t)t * BATCH + b) << 11) + c] = (float)S;
    }
}
#undef OFF_OF

// ---------------------------------------------------------------------------
extern "C" void kernel_launch(void* const* d_in, const int* in_sizes, int n_in,
                              void* d_out, int out_size, void* d_ws, size_t ws_size,
                              hipStream_t stream)
{
    const float* rates = (const float*)d_in[0];
    const float* noise = (const float*)d_in[1];
    const float* Win   = (const float*)d_in[2];
    const float* Wrec  = (const float*)d_in[3];
    float* out = (float*)d_out;

    // workspace layout (bytes):
    //   [0, 204800)           xi_mask uint32[T][B][16]
    //   [204800, 270336)      smask   u64[2][B][128]  (tag<<32 | mask)
    //   [270336, +52428800)   Iff     float[T][B][A][N]  (16B aligned)
    char* ws = (char*)d_ws;
    unsigned* xi_mask = (unsigned*)ws;
    unsigned long long* smask = (unsigned long long*)(ws + 204800);
    float* Iff = (float*)(ws + 270336);

    hipMemsetAsync(d_ws, 0, 270336, stream);   // zero xi_mask + smask

    k0_xi<<<6400, 256, 0, stream>>>(rates, noise, out, xi_mask);
    k_ff<<<dim3(3200, 2), 256, 0, stream>>>(Win, xi_mask, Iff);

    float* outS = out + (size_t)T_STEPS * BATCH * NIN;
    void* args[] = { (void*)&Wrec, (void*)&smask, (void*)&Iff, (void*)&outS };
    hipLaunchCooperativeKernel((const void*)k_steps, dim3(512), dim3(256),
                               args, 0, stream);
}